// Round 6
// baseline (109.924 us; speedup 1.0000x reference)
//
#include <hip/hip_runtime.h>
#include <stdint.h>
#include <math.h>

constexpr int BROWS = 256;
constexpr int VCOLS = 128000;
constexpr int NQ    = 5;                 // fifth-rows: 25600 cols each
constexpr int QCOLS = VCOLS / NQ;        // 25600
constexpr int QV4   = QCOLS / 4;         // 6400 float4 per fifth
constexpr int NBLK  = BROWS * NQ;        // 1280 blocks = 5 per CU exactly
constexpr int NTHR  = 256;               // 4 waves per block; 6400/256 = 25 iters exact

// ---------- sortable float <-> uint mapping (order-isomorphic) --------------
__device__ __forceinline__ uint32_t fmap(float v) {
  uint32_t b = __float_as_uint(v);
  return b ^ (uint32_t)(((int32_t)b >> 31) | 0x80000000);
}
__device__ __forceinline__ float funmap(uint32_t s) {
  uint32_t b = s ^ (uint32_t)(((~(int32_t)s) >> 31) | 0x80000000);
  return __uint_as_float(b);
}

// key = (sortable_value << 32) | ~idx  -> u64 max == (max value, then min idx)
__device__ __forceinline__ unsigned long long mkkey(uint32_t s, int idx) {
  return ((unsigned long long)s << 32) | (uint32_t)(~(uint32_t)idx);
}

// ---------- Threefry-2x32, key (0,1) [jax.random.key(1)], partitionable -----
// ks = [0, 1, 0x1BD11BDB]; counter (0, i); bits = out0 ^ out1.
__device__ __forceinline__ uint32_t rotl(uint32_t x, uint32_t r) {
  return __builtin_amdgcn_alignbit(x, x, 32u - r);
}
// Takes x1_init = counter_lo + 1 (first key-injection pre-applied).
__device__ __forceinline__ uint32_t tf_bits_x1(uint32_t x1i) {
  uint32_t x0 = 0u;
  uint32_t x1 = x1i;
#define R4(r0,r1,r2,r3) \
  x0 += x1; x1 = rotl(x1, r0); x1 ^= x0; \
  x0 += x1; x1 = rotl(x1, r1); x1 ^= x0; \
  x0 += x1; x1 = rotl(x1, r2); x1 ^= x0; \
  x0 += x1; x1 = rotl(x1, r3); x1 ^= x0;
  R4(13u,15u,26u,6u)
  x0 += 1u;            x1 += 0x1BD11BDBu + 1u;
  R4(17u,29u,16u,24u)
  x0 += 0x1BD11BDBu;   x1 += 0u + 2u;
  R4(13u,15u,26u,6u)
  /* x0 += 0 */        x1 += 1u + 3u;
  R4(17u,29u,16u,24u)
  x0 += 1u;            x1 += 0x1BD11BDBu + 4u;
  R4(13u,15u,26u,6u)
  x0 += 0x1BD11BDBu;   x1 += 0u + 5u;
#undef R4
  return x0 ^ x1;
}

// ---------- block reduce of u64-max (NTHR/64 waves) -------------------------
__device__ __forceinline__ unsigned long long blockMaxU64(unsigned long long v) {
  __shared__ unsigned long long s_w[NTHR / 64];
  const int wid = threadIdx.x >> 6, lane = threadIdx.x & 63;
  #pragma unroll
  for (int off = 32; off > 0; off >>= 1) {
    unsigned long long o = __shfl_xor(v, off, 64);
    if (o > v) v = o;
  }
  if (lane == 0) s_w[wid] = v;
  __syncthreads();
  if (threadIdx.x == 0) {
    #pragma unroll
    for (int w = 1; w < NTHR / 64; ++w) if (s_w[w] > v) v = s_w[w];
    s_w[0] = v;
  }
  __syncthreads();
  return s_w[0];
}

// ================== K1: per-fifth raw-logit max/argmax ======================
extern "C" __global__ void __launch_bounds__(NTHR)
k1_rowmax(const float* __restrict__ logits,
          unsigned long long* __restrict__ partMax)
{
  const int blk = blockIdx.x;
  const int row = blk / NQ, q = blk % NQ;
  const float4* base =
      reinterpret_cast<const float4*>(logits + (size_t)row * VCOLS + q * QCOLS);
  const int idx0 = q * QCOLS;

  unsigned long long best = 0ull;
  for (int vv = threadIdx.x; vv < QV4; vv += NTHR) {
    float4 l4 = base[vv];
    int v0 = idx0 + vv * 4;
    unsigned long long k0 = mkkey(fmap(l4.x), v0 + 0);
    unsigned long long k1 = mkkey(fmap(l4.y), v0 + 1);
    unsigned long long k2 = mkkey(fmap(l4.z), v0 + 2);
    unsigned long long k3 = mkkey(fmap(l4.w), v0 + 3);
    if (k1 > k0) k0 = k1;
    if (k3 > k2) k2 = k3;
    if (k2 > k0) k0 = k2;
    if (k0 > best) best = k0;
  }
  best = blockMaxU64(best);
  if (threadIdx.x == 0) partMax[blk] = best;
}

// ================== K2: per-fifth exponential-race argmax ===================
// Log-domain: val = fma(l, c1, c0) - log2|log2(2-f)|, c1 = log2e/t,
// c0 = -M*c1 - log2(ln2). Monotone in ratio; noise==0 (f==1) -> +inf; no NaN.
extern "C" __global__ void __launch_bounds__(NTHR)
k2_sample(const float* __restrict__ logits,
          const float* __restrict__ temps,
          const unsigned long long* __restrict__ partMax,
          unsigned long long* __restrict__ sampPart)
{
  const int blk = blockIdx.x;
  const int row = blk / NQ, q = blk % NQ;
  const float4* base =
      reinterpret_cast<const float4*>(logits + (size_t)row * VCOLS + q * QCOLS);

  const float t = temps[row];
  const float safe_t = (t == 0.0f) ? 1.0f : t;
  const float inv_t = 1.0f / safe_t;

  // combine the row's partials -> row max logit M
  unsigned long long pm = partMax[row * NQ];
  #pragma unroll
  for (int j = 1; j < NQ; ++j) {
    unsigned long long o = partMax[row * NQ + j];
    if (o > pm) pm = o;
  }
  const float M = funmap((uint32_t)(pm >> 32));

  const float c1 = inv_t * 1.4426950408889634f;           // log2(e)/t
  const float c0 = fmaf(-M, c1, 0.5287663729448977f);     // -M*c1 - log2(ln2)

  const uint32_t rowbase = (uint32_t)row * (uint32_t)VCOLS;
  const uint32_t Ce = rowbase + (uint32_t)(q * QCOLS) + 1u; // counter+1 base

  float bestv = -INFINITY;
  uint32_t bestx1 = 0u;

  for (int vv = threadIdx.x; vv < QV4; vv += NTHR) {
    float4 l4 = base[vv];
    const uint32_t ce = Ce + (uint32_t)(vv * 4);
    const float lx[4] = {l4.x, l4.y, l4.z, l4.w};
    #pragma unroll
    for (uint32_t k = 0; k < 4; ++k) {
      uint32_t x1i = ce + k;                       // == counter_lo + 1
      uint32_t bits = tf_bits_x1(x1i);
      // f in [1,2); 2-f exact (Sterbenz); g = log2(2-f) = log2(1-u).
      float f = __uint_as_float((bits >> 9) | 0x3F800000u);
      float g = __builtin_amdgcn_logf(2.0f - f);         // v_log_f32
      float ln_noise2 = __builtin_amdgcn_logf(fabsf(g)); // log2|g| (|.| = free mod)
      float val = fmaf(lx[k], c1, c0) - ln_noise2;       // +inf when g==0
      if (val > bestv) { bestv = val; bestx1 = x1i; }
    }
  }

  // recover column index within the row from the tracked x1-init
  const int colidx = (int)(bestx1 - 1u - rowbase);
  unsigned long long best = mkkey(fmap(bestv), colidx);
  best = blockMaxU64(best);
  if (threadIdx.x == 0) sampPart[blk] = best;
}

// ================== K3: combine fifths, greedy/sample select ================
extern "C" __global__ void __launch_bounds__(BROWS)
k3_final(const float* __restrict__ temps,
         const unsigned long long* __restrict__ partMax,
         const unsigned long long* __restrict__ sampPart,
         int* __restrict__ out)
{
  const int r = threadIdx.x;
  if (r >= BROWS) return;
  unsigned long long g = partMax[r * NQ];
  unsigned long long s = sampPart[r * NQ];
  #pragma unroll
  for (int j = 1; j < NQ; ++j) {
    unsigned long long og = partMax[r * NQ + j];
    unsigned long long os = sampPart[r * NQ + j];
    if (og > g) g = og;
    if (os > s) s = os;
  }
  const int greedy = (int)(~(uint32_t)g);
  const int samp   = (int)(~(uint32_t)s);
  out[r] = (temps[r] == 0.0f) ? greedy : samp;
}

extern "C" void kernel_launch(void* const* d_in, const int* in_sizes, int n_in,
                              void* d_out, int out_size, void* d_ws, size_t ws_size,
                              hipStream_t stream) {
  const float* logits = (const float*)d_in[0];
  const float* temps  = (const float*)d_in[1];
  int* out = (int*)d_out;

  unsigned long long* partMax  = (unsigned long long*)d_ws;            // NBLK entries
  unsigned long long* sampPart = partMax + NBLK;                       // NBLK entries

  k1_rowmax<<<NBLK, NTHR, 0, stream>>>(logits, partMax);
  k2_sample<<<NBLK, NTHR, 0, stream>>>(logits, temps, partMax, sampPart);
  k3_final<<<1, BROWS, 0, stream>>>(temps, partMax, sampPart, out);
}

// Round 7
// 97.035 us; speedup vs baseline: 1.1328x; 1.1328x over previous
//
#include <hip/hip_runtime.h>
#include <stdint.h>
#include <math.h>

constexpr int BROWS = 256;
constexpr int VCOLS = 128000;
constexpr int NQ    = 5;                 // fifth-rows: 25600 cols each
constexpr int QCOLS = VCOLS / NQ;        // 25600
constexpr int QV4   = QCOLS / 4;         // 6400 float4 per fifth
constexpr int NBLK  = BROWS * NQ;        // 1280 blocks = 5 per CU exactly
constexpr int NTHR  = 320;               // 5 waves; 6400/(320*4) = 5 outer iters
constexpr int NITER = QV4 / (NTHR * 4);  // 5

// ---------- sortable float <-> uint mapping (order-isomorphic) --------------
__device__ __forceinline__ uint32_t fmap(float v) {
  uint32_t b = __float_as_uint(v);
  return b ^ (uint32_t)(((int32_t)b >> 31) | 0x80000000);
}
__device__ __forceinline__ float funmap(uint32_t s) {
  uint32_t b = s ^ (uint32_t)(((~(int32_t)s) >> 31) | 0x80000000);
  return __uint_as_float(b);
}

// key = (sortable_value << 32) | ~idx  -> u64 max == (max value, then min idx)
__device__ __forceinline__ unsigned long long mkkey(uint32_t s, int idx) {
  return ((unsigned long long)s << 32) | (uint32_t)(~(uint32_t)idx);
}

// ---------- Threefry-2x32, key (0,1) [jax.random.key(1)], partitionable -----
// ks = [0, 1, 0x1BD11BDB]; counter (0, i); bits = out0 ^ out1.
__device__ __forceinline__ uint32_t rotl(uint32_t x, uint32_t r) {
  return __builtin_amdgcn_alignbit(x, x, 32u - r);
}
// Takes x1_init = counter_lo + 1 (first key-injection pre-applied).
__device__ __forceinline__ uint32_t tf_bits_x1(uint32_t x1i) {
  uint32_t x0 = 0u;
  uint32_t x1 = x1i;
#define R4(r0,r1,r2,r3) \
  x0 += x1; x1 = rotl(x1, r0); x1 ^= x0; \
  x0 += x1; x1 = rotl(x1, r1); x1 ^= x0; \
  x0 += x1; x1 = rotl(x1, r2); x1 ^= x0; \
  x0 += x1; x1 = rotl(x1, r3); x1 ^= x0;
  R4(13u,15u,26u,6u)
  x0 += 1u;            x1 += 0x1BD11BDBu + 1u;
  R4(17u,29u,16u,24u)
  x0 += 0x1BD11BDBu;   x1 += 0u + 2u;
  R4(13u,15u,26u,6u)
  /* x0 += 0 */        x1 += 1u + 3u;
  R4(17u,29u,16u,24u)
  x0 += 1u;            x1 += 0x1BD11BDBu + 4u;
  R4(13u,15u,26u,6u)
  x0 += 0x1BD11BDBu;   x1 += 0u + 5u;
#undef R4
  return x0 ^ x1;
}

// ---------- block reduce of u64-max -----------------------------------------
template <int NT>
__device__ __forceinline__ unsigned long long blockMaxU64(unsigned long long v) {
  __shared__ unsigned long long s_w[NT / 64];
  const int wid = threadIdx.x >> 6, lane = threadIdx.x & 63;
  #pragma unroll
  for (int off = 32; off > 0; off >>= 1) {
    unsigned long long o = __shfl_xor(v, off, 64);
    if (o > v) v = o;
  }
  if (lane == 0) s_w[wid] = v;
  __syncthreads();
  if (threadIdx.x == 0) {
    #pragma unroll
    for (int w = 1; w < NT / 64; ++w) if (s_w[w] > v) v = s_w[w];
    s_w[0] = v;
  }
  __syncthreads();
  return s_w[0];
}

// ================== K1: per-fifth raw-logit max/argmax ======================
extern "C" __global__ void __launch_bounds__(NTHR)
k1_rowmax(const float* __restrict__ logits,
          unsigned long long* __restrict__ partMax)
{
  const int blk = blockIdx.x;
  const int row = blk / NQ, q = blk % NQ;
  const float4* base =
      reinterpret_cast<const float4*>(logits + (size_t)row * VCOLS + q * QCOLS);
  const int idx0 = q * QCOLS;

  unsigned long long best = 0ull;
  for (int vv = threadIdx.x; vv < QV4; vv += NTHR) {
    float4 l4 = base[vv];
    int v0 = idx0 + vv * 4;
    unsigned long long k0 = mkkey(fmap(l4.x), v0 + 0);
    unsigned long long k1 = mkkey(fmap(l4.y), v0 + 1);
    unsigned long long k2 = mkkey(fmap(l4.z), v0 + 2);
    unsigned long long k3 = mkkey(fmap(l4.w), v0 + 3);
    if (k1 > k0) k0 = k1;
    if (k3 > k2) k2 = k3;
    if (k2 > k0) k0 = k2;
    if (k0 > best) best = k0;
  }
  best = blockMaxU64<NTHR>(best);
  if (threadIdx.x == 0) partMax[blk] = best;
}

// ================== K2: per-fifth exponential-race argmax ===================
// Log-domain: val = fma(l, c1, c0) - log2|log2(2-f)|, c1 = log2e/t,
// c0 = -M*c1 - log2(ln2). Monotone in ratio; noise==0 (f==1) -> +inf; no NaN.
// 16 elements (4 coalesced float4 loads) in flight per iteration for ILP.
extern "C" __global__ void __launch_bounds__(NTHR)
k2_sample(const float* __restrict__ logits,
          const float* __restrict__ temps,
          const unsigned long long* __restrict__ partMax,
          unsigned long long* __restrict__ sampPart)
{
  const int blk = blockIdx.x;
  const int row = blk / NQ, q = blk % NQ;
  const float4* base =
      reinterpret_cast<const float4*>(logits + (size_t)row * VCOLS + q * QCOLS);

  const float t = temps[row];
  const float safe_t = (t == 0.0f) ? 1.0f : t;
  const float inv_t = 1.0f / safe_t;

  // combine the row's partials -> row max logit M
  unsigned long long pm = partMax[row * NQ];
  #pragma unroll
  for (int j = 1; j < NQ; ++j) {
    unsigned long long o = partMax[row * NQ + j];
    if (o > pm) pm = o;
  }
  const float M = funmap((uint32_t)(pm >> 32));

  const float c1 = inv_t * 1.4426950408889634f;           // log2(e)/t
  const float c0 = fmaf(-M, c1, 0.5287663729448977f);     // -M*c1 - log2(ln2)

  const uint32_t rowbase = (uint32_t)row * (uint32_t)VCOLS;
  // x1-init for column c (within row): rowbase + c + 1
  const uint32_t Ce = rowbase + (uint32_t)(q * QCOLS) + 1u;

  float bestv = -INFINITY;
  uint32_t bestx1 = 0u;

  #pragma unroll
  for (int it = 0; it < NITER; ++it) {
    const int vbase = it * (NTHR * 4) + (int)threadIdx.x;
    // issue all 4 coalesced loads up front (independent, one vmcnt window)
    float4 L[4];
    #pragma unroll
    for (int u = 0; u < 4; ++u) L[u] = base[vbase + u * NTHR];

    #pragma unroll
    for (int u = 0; u < 4; ++u) {
      const uint32_t ce = Ce + (uint32_t)((vbase + u * NTHR) * 4);
      const float lx[4] = {L[u].x, L[u].y, L[u].z, L[u].w};
      #pragma unroll
      for (uint32_t k = 0; k < 4; ++k) {
        uint32_t x1i = ce + k;                       // == counter_lo + 1
        uint32_t bits = tf_bits_x1(x1i);
        // f in [1,2); 2-f exact (Sterbenz); g = log2(2-f) = log2(1-u).
        float f = __uint_as_float((bits >> 9) | 0x3F800000u);
        float g = __builtin_amdgcn_logf(2.0f - f);         // v_log_f32
        float ln_noise2 = __builtin_amdgcn_logf(fabsf(g)); // log2|g|
        float val = fmaf(lx[k], c1, c0) - ln_noise2;       // +inf when g==0
        if (val > bestv) { bestv = val; bestx1 = x1i; }
      }
    }
  }

  // recover column index within the row from the tracked x1-init
  const int colidx = (int)(bestx1 - 1u - rowbase);
  unsigned long long best = mkkey(fmap(bestv), colidx);
  best = blockMaxU64<NTHR>(best);
  if (threadIdx.x == 0) sampPart[blk] = best;
}

// ================== K3: combine fifths, greedy/sample select ================
extern "C" __global__ void __launch_bounds__(BROWS)
k3_final(const float* __restrict__ temps,
         const unsigned long long* __restrict__ partMax,
         const unsigned long long* __restrict__ sampPart,
         int* __restrict__ out)
{
  const int r = threadIdx.x;
  if (r >= BROWS) return;
  unsigned long long g = partMax[r * NQ];
  unsigned long long s = sampPart[r * NQ];
  #pragma unroll
  for (int j = 1; j < NQ; ++j) {
    unsigned long long og = partMax[r * NQ + j];
    unsigned long long os = sampPart[r * NQ + j];
    if (og > g) g = og;
    if (os > s) s = os;
  }
  const int greedy = (int)(~(uint32_t)g);
  const int samp   = (int)(~(uint32_t)s);
  out[r] = (temps[r] == 0.0f) ? greedy : samp;
}

extern "C" void kernel_launch(void* const* d_in, const int* in_sizes, int n_in,
                              void* d_out, int out_size, void* d_ws, size_t ws_size,
                              hipStream_t stream) {
  const float* logits = (const float*)d_in[0];
  const float* temps  = (const float*)d_in[1];
  int* out = (int*)d_out;

  unsigned long long* partMax  = (unsigned long long*)d_ws;            // NBLK entries
  unsigned long long* sampPart = partMax + NBLK;                       // NBLK entries

  k1_rowmax<<<NBLK, NTHR, 0, stream>>>(logits, partMax);
  k2_sample<<<NBLK, NTHR, 0, stream>>>(logits, temps, partMax, sampPart);
  k3_final<<<1, BROWS, 0, stream>>>(temps, partMax, sampPart, out);
}

// Round 8
// 81.722 us; speedup vs baseline: 1.3451x; 1.1874x over previous
//
#include <hip/hip_runtime.h>
#include <stdint.h>
#include <math.h>

constexpr int BROWS = 256;
constexpr int VCOLS = 128000;
constexpr int NQ    = 5;                 // fifth-rows: 25600 cols each
constexpr int QCOLS = VCOLS / NQ;        // 25600
constexpr int QV4   = QCOLS / 4;         // 6400 float4 per fifth
constexpr int NBLK  = BROWS * NQ;        // 1280 blocks = 5 per CU exactly
constexpr int NTHR  = 320;               // 5 waves; 6400/(320*4) = 5 outer iters
constexpr int NITER = QV4 / (NTHR * 4);  // 5

// ---------- sortable float -> uint mapping (order-isomorphic) ---------------
__device__ __forceinline__ uint32_t fmap(float v) {
  uint32_t b = __float_as_uint(v);
  return b ^ (uint32_t)(((int32_t)b >> 31) | 0x80000000);
}

// key = (sortable_value << 32) | ~idx  -> u64 max == (max value, then min idx)
__device__ __forceinline__ unsigned long long mkkey(uint32_t s, int idx) {
  return ((unsigned long long)s << 32) | (uint32_t)(~(uint32_t)idx);
}

__device__ __forceinline__ uint32_t rotl(uint32_t x, uint32_t r) {
  return __builtin_amdgcn_alignbit(x, x, 32u - r);
}

// ---------- 4-lockstep Threefry-2x32, key (0,1), partitionable --------------
// ks = [0, 1, 0x1BD11BDB]; counter (0, i); bits = out0 ^ out1.
// Inputs are x1-inits (= counter_lo + 1, first key-injection pre-applied).
// Four chains interleaved in program order for ILP.
__device__ __forceinline__ void tf4_bits(uint32_t i0, uint32_t i1, uint32_t i2,
                                         uint32_t i3, uint32_t o[4]) {
  uint32_t a0, a1, a2, a3;
  uint32_t b0 = i0, b1 = i1, b2 = i2, b3 = i3;
#define RND(r) \
  a0 += b0; b0 = rotl(b0, r) ^ a0; \
  a1 += b1; b1 = rotl(b1, r) ^ a1; \
  a2 += b2; b2 = rotl(b2, r) ^ a2; \
  a3 += b3; b3 = rotl(b3, r) ^ a3;
  // round 1 with a==0 folded: a = b; b = rotl(b,13) ^ a
  a0 = b0; b0 = rotl(b0, 13u) ^ a0;
  a1 = b1; b1 = rotl(b1, 13u) ^ a1;
  a2 = b2; b2 = rotl(b2, 13u) ^ a2;
  a3 = b3; b3 = rotl(b3, 13u) ^ a3;
  RND(15u) RND(26u) RND(6u)
  a0 += 1u; a1 += 1u; a2 += 1u; a3 += 1u;
  b0 += 0x1BD11BDCu; b1 += 0x1BD11BDCu; b2 += 0x1BD11BDCu; b3 += 0x1BD11BDCu;
  RND(17u) RND(29u) RND(16u) RND(24u)
  a0 += 0x1BD11BDBu; a1 += 0x1BD11BDBu; a2 += 0x1BD11BDBu; a3 += 0x1BD11BDBu;
  b0 += 2u; b1 += 2u; b2 += 2u; b3 += 2u;
  RND(13u) RND(15u) RND(26u) RND(6u)
  b0 += 4u; b1 += 4u; b2 += 4u; b3 += 4u;   // ks[1]+3 = 4; a += ks[0]==0
  RND(17u) RND(29u) RND(16u) RND(24u)
  a0 += 1u; a1 += 1u; a2 += 1u; a3 += 1u;
  b0 += 0x1BD11BDFu; b1 += 0x1BD11BDFu; b2 += 0x1BD11BDFu; b3 += 0x1BD11BDFu; // ks[2]+4
  RND(13u) RND(15u) RND(26u) RND(6u)
  a0 += 0x1BD11BDBu; a1 += 0x1BD11BDBu; a2 += 0x1BD11BDBu; a3 += 0x1BD11BDBu;
  b0 += 5u; b1 += 5u; b2 += 5u; b3 += 5u;
#undef RND
  o[0] = a0 ^ b0; o[1] = a1 ^ b1; o[2] = a2 ^ b2; o[3] = a3 ^ b3;
}

// ---------- block reduce of u64-max -----------------------------------------
template <int NT>
__device__ __forceinline__ unsigned long long blockMaxU64(unsigned long long v) {
  __shared__ unsigned long long s_w[NT / 64];
  const int wid = threadIdx.x >> 6, lane = threadIdx.x & 63;
  #pragma unroll
  for (int off = 32; off > 0; off >>= 1) {
    unsigned long long o = __shfl_xor(v, off, 64);
    if (o > v) v = o;
  }
  if (lane == 0) s_w[wid] = v;
  __syncthreads();
  if (threadIdx.x == 0) {
    #pragma unroll
    for (int w = 1; w < NT / 64; ++w) if (s_w[w] > v) v = s_w[w];
    s_w[0] = v;
  }
  __syncthreads();
  return s_w[0];
}

// ============ K-main: fused greedy-argmax + exponential-race argmax =========
// Sample value: val = l*c1 - log2|log2(2-f)|  (row constant c0 dropped: it
// cannot change the row argmax). c1 = log2(e)/safe_t. No NaN possible;
// noise==0 (f==1) -> val=+inf, matching ratio=+inf in the reference.
extern "C" __global__ void __launch_bounds__(NTHR)
k_main(const float* __restrict__ logits,
       const float* __restrict__ temps,
       unsigned long long* __restrict__ gPart,
       unsigned long long* __restrict__ sPart)
{
  const int blk = blockIdx.x;
  const int row = blk / NQ, q = blk % NQ;
  const float4* base =
      reinterpret_cast<const float4*>(logits + (size_t)row * VCOLS + q * QCOLS);

  const float t = temps[row];
  const float safe_t = (t == 0.0f) ? 1.0f : t;
  const float c1 = (1.0f / safe_t) * 1.4426950408889634f;   // log2(e)/t

  const uint32_t rowbase = (uint32_t)row * (uint32_t)VCOLS;
  const uint32_t Ce = rowbase + (uint32_t)(q * QCOLS) + 1u; // x1-init base

  float gv = -INFINITY; uint32_t gx = 0u;   // greedy: raw logit
  float bv = -INFINITY; uint32_t bx = 0u;   // sample: race value

  int vb = (int)threadIdx.x;
  float4 A0 = base[vb], A1 = base[vb + NTHR],
         A2 = base[vb + 2 * NTHR], A3 = base[vb + 3 * NTHR];

  #pragma unroll 1
  for (int it = 0; it < NITER; ++it) {
    const int nvb = vb + 4 * NTHR;
    float4 B0, B1, B2, B3;
    if (it + 1 < NITER) {                     // uniform branch; prefetch next
      B0 = base[nvb]; B1 = base[nvb + NTHR];
      B2 = base[nvb + 2 * NTHR]; B3 = base[nvb + 3 * NTHR];
    }

    const float4 As[4] = {A0, A1, A2, A3};
    #pragma unroll
    for (int u = 0; u < 4; ++u) {
      const uint32_t ce = Ce + (uint32_t)((vb + u * NTHR) * 4);
      const float lx[4] = {As[u].x, As[u].y, As[u].z, As[u].w};
      uint32_t bits[4];
      tf4_bits(ce, ce + 1u, ce + 2u, ce + 3u, bits);
      #pragma unroll
      for (uint32_t k = 0; k < 4; ++k) {
        const uint32_t x1i = ce + k;
        // f in [1,2); 2-f exact (Sterbenz); g = log2(2-f) = log2(1-u).
        float f = __uint_as_float((bits[k] >> 9) | 0x3F800000u);
        float g = __builtin_amdgcn_logf(2.0f - f);          // v_log_f32
        float g2 = __builtin_amdgcn_logf(fabsf(g));         // log2|g|
        float val = fmaf(lx[k], c1, -g2);                   // +inf when g==0
        if (lx[k] > gv) { gv = lx[k]; gx = x1i; }           // greedy track
        if (val  > bv) { bv = val;    bx = x1i; }           // sample track
      }
    }

    vb = nvb;
    A0 = B0; A1 = B1; A2 = B2; A3 = B3;
  }

  const int gcol = (int)(gx - 1u - rowbase);
  const int scol = (int)(bx - 1u - rowbase);
  unsigned long long gk = blockMaxU64<NTHR>(mkkey(fmap(gv), gcol));
  unsigned long long sk = blockMaxU64<NTHR>(mkkey(fmap(bv), scol));
  if (threadIdx.x == 0) { gPart[blk] = gk; sPart[blk] = sk; }
}

// ================== K3: combine fifths, greedy/sample select ================
extern "C" __global__ void __launch_bounds__(BROWS)
k3_final(const float* __restrict__ temps,
         const unsigned long long* __restrict__ gPart,
         const unsigned long long* __restrict__ sPart,
         int* __restrict__ out)
{
  const int r = threadIdx.x;
  if (r >= BROWS) return;
  unsigned long long g = gPart[r * NQ];
  unsigned long long s = sPart[r * NQ];
  #pragma unroll
  for (int j = 1; j < NQ; ++j) {
    unsigned long long og = gPart[r * NQ + j];
    unsigned long long os = sPart[r * NQ + j];
    if (og > g) g = og;
    if (os > s) s = os;
  }
  const int greedy = (int)(~(uint32_t)g);
  const int samp   = (int)(~(uint32_t)s);
  out[r] = (temps[r] == 0.0f) ? greedy : samp;
}

extern "C" void kernel_launch(void* const* d_in, const int* in_sizes, int n_in,
                              void* d_out, int out_size, void* d_ws, size_t ws_size,
                              hipStream_t stream) {
  const float* logits = (const float*)d_in[0];
  const float* temps  = (const float*)d_in[1];
  int* out = (int*)d_out;

  unsigned long long* gPart = (unsigned long long*)d_ws;   // NBLK entries
  unsigned long long* sPart = gPart + NBLK;                // NBLK entries

  k_main<<<NBLK, NTHR, 0, stream>>>(logits, temps, gPart, sPart);
  k3_final<<<1, BROWS, 0, stream>>>(temps, gPart, sPart, out);
}